// Round 2
// baseline (102.955 us; speedup 1.0000x reference)
//
#include <hip/hip_runtime.h>

#define B_ 32
#define PRE_ 2048
#define POST_ 2048
#define QT 4             // q rows per WG in forward kernel
#define WPAD 2056        // LDS row stride (shorts); 2056*2B = 16B-multiple

// ws layout (unsigned short elements):
//   frag [2048][64]   @ 65536   per p: [ tp_bf16(32) | x_bf16(32) ]  - dw A-frags
//   spq  [2048][64]   @ 196608  per q: [ sp_bf16(32) | -tq_bf16(32) ] - dw B-frags
#define FRAG_OFF 65536
#define SPQ_OFF  196608

typedef __attribute__((ext_vector_type(8))) short short8;
typedef __attribute__((ext_vector_type(4))) short short4v;
typedef __attribute__((ext_vector_type(4))) float floatx4;

__device__ __forceinline__ unsigned short f2bf(float f) {
    unsigned u = __float_as_uint(f);
    u += 0x7FFF + ((u >> 16) & 1);   // round-to-nearest-even
    return (unsigned short)(u >> 16);
}
__device__ __forceinline__ float bf2f(unsigned short h) {
    return __uint_as_float(((unsigned)h) << 16);
}

// K_A: forward + frag-transpose side-job. 512 WGs x 512 threads, 32.9KB LDS
// (red aliases dead Wh region after the forward barrier) -> 2 WGs/CU.
// Forward A-frags convert x fp32->bf16 on the fly (exact for {0,1}); the
// xrow staging buffer and the separate prep kernel are gone.
__global__ __launch_bounds__(512) void stdp_fwd(
    const float* __restrict__ W, const float* __restrict__ x,
    const float* __restrict__ tpre, const float* __restrict__ tpost,
    unsigned short* __restrict__ ws, float* __restrict__ out)
{
    __shared__ __align__(16) unsigned short sh[2 * QT * WPAD];   // 32.9 KB
    unsigned short* Wh = sh;
    unsigned short* Wl = sh + QT * WPAD;
    float* red = (float*)sh;   // 16 KB, aliases Wh after __syncthreads

    const int tid  = threadIdx.x;
    const int wave = tid >> 6, lane = tid & 63;
    const int quad = lane >> 4, l16 = lane & 15;
    const int q0   = blockIdx.x * QT;
    const int qb   = l16 & (QT - 1);
    const int kbase = wave * 256;     // wave's K-slice (wave-private LDS columns)

    // ---- side job (wave 7, lanes 0..31): build frag rows p0..p0+3 for the dw
    // kernel. 16B row reads; stores are 64B-coalesced across 32 lanes.
    if (wave == 7 && lane < 32) {
        const int p0 = blockIdx.x * 4;
        unsigned short* frag = ws + FRAG_OFF;
        floatx4 xv = *(const floatx4*)(x    + lane * PRE_ + p0);
        floatx4 tv = *(const floatx4*)(tpre + lane * PRE_ + p0);
#pragma unroll
        for (int c = 0; c < 4; ++c) {
            frag[(p0 + c) * 64 + lane]      = f2bf(0.5f * tv[c] + xv[c]);
            frag[(p0 + c) * 64 + 32 + lane] =
                (unsigned short)(__float_as_uint(xv[c]) >> 16);   // exact {0,1}
        }
    }

    float tpr[4];
    if (wave < 2 && l16 < QT) {
#pragma unroll
        for (int r = 0; r < 4; ++r)
            tpr[r] = tpost[(wave * 16 + quad * 4 + r) * POST_ + q0 + l16];
    }

    // ---- stage W rows q0..q0+3, cols [kbase, kbase+256) as split bf16 ----
    floatx4 wv[QT];
#pragma unroll
    for (int r = 0; r < QT; ++r)
        wv[r] = *(const floatx4*)(W + (q0 + r) * PRE_ + kbase + lane * 4);
#pragma unroll
    for (int r = 0; r < QT; ++r) {
        short4v hv, lv;
#pragma unroll
        for (int j = 0; j < 4; ++j) {
            unsigned short h = f2bf(wv[r][j]);
            hv[j] = (short)h;
            lv[j] = (short)f2bf(wv[r][j] - bf2f(h));
        }
        *(short4v*)&Wh[r * WPAD + kbase + lane * 4] = hv;
        *(short4v*)&Wl[r * WPAD + kbase + lane * 4] = lv;
    }

    // ---- forward partial over this wave's K-slice; x converted on the fly ----
    floatx4 acc0 = {0.f, 0.f, 0.f, 0.f};
    floatx4 acc1 = {0.f, 0.f, 0.f, 0.f};
#pragma unroll
    for (int s = 0; s < 8; ++s) {
        int ko = kbase + s * 32 + quad * 8;
        floatx4 xa0 = *(const floatx4*)(x + l16 * PRE_ + ko);
        floatx4 xa1 = *(const floatx4*)(x + l16 * PRE_ + ko + 4);
        floatx4 xb0 = *(const floatx4*)(x + (16 + l16) * PRE_ + ko);
        floatx4 xb1 = *(const floatx4*)(x + (16 + l16) * PRE_ + ko + 4);
        short8 a0, a1;
#pragma unroll
        for (int j = 0; j < 4; ++j) {
            a0[j]     = (short)(__float_as_uint(xa0[j]) >> 16);
            a0[4 + j] = (short)(__float_as_uint(xa1[j]) >> 16);
            a1[j]     = (short)(__float_as_uint(xb0[j]) >> 16);
            a1[4 + j] = (short)(__float_as_uint(xb1[j]) >> 16);
        }
        short8 bh = *(const short8*)(Wh + qb * WPAD + ko);
        short8 bl = *(const short8*)(Wl + qb * WPAD + ko);
        acc0 = __builtin_amdgcn_mfma_f32_16x16x32_bf16(a0, bh, acc0, 0, 0, 0);
        acc0 = __builtin_amdgcn_mfma_f32_16x16x32_bf16(a0, bl, acc0, 0, 0, 0);
        acc1 = __builtin_amdgcn_mfma_f32_16x16x32_bf16(a1, bh, acc1, 0, 0, 0);
        acc1 = __builtin_amdgcn_mfma_f32_16x16x32_bf16(a1, bl, acc1, 0, 0, 0);
    }

    __syncthreads();                 // all waves done reading Wh/Wl
#pragma unroll
    for (int r = 0; r < 4; ++r) {
        red[((wave * 2 + 0) * 4 + r) * 64 + lane] = acc0[r];
        red[((wave * 2 + 1) * 4 + r) * 64 + lane] = acc1[r];
    }
    __syncthreads();

    if (wave < 2 && l16 < QT) {
        unsigned short* spq = ws + SPQ_OFF;
        int q = q0 + l16;
#pragma unroll
        for (int r = 0; r < 4; ++r) {
            float s = 0.f;
#pragma unroll
            for (int w = 0; w < 8; ++w) s += red[((w * 2 + wave) * 4 + r) * 64 + lane];
            int b = wave * 16 + quad * 4 + r;
            float spike = (s >= 1.0f) ? 1.0f : 0.0f;
            out[b * POST_ + q] = spike;
            float ntq = -(0.5f * tpr[r] + spike);     // -tq, single rounded bf16
            spq[q * 64 + b]      = f2bf(spike);
            spq[q * 64 + 32 + b] = f2bf(ntq);
        }
    }
}

// K_B: dw. Zero LDS, 1024 WGs, 16 DISTINCT q per MFMA tile.
// Operand order mfma(frag_p, spq_q) puts D-rows on p, so W-clamp load and dw
// store are one float4 per lane. W is L3-resident after K_A; XCD swizzle gives
// each XCD a 2MB L2-resident W slice.
__global__ __launch_bounds__(256) void stdp_dw(
    const float* __restrict__ W, const unsigned short* __restrict__ ws,
    float* __restrict__ out)
{
    const unsigned short* frag = ws + FRAG_OFF;
    const unsigned short* spq  = ws + SPQ_OFF;
    float* dw = out + B_ * POST_;

    const int tid  = threadIdx.x;
    const int wave = tid >> 6, lane = tid & 63;
    const int quad = lane >> 4, l16 = lane & 15;
    // bijective XCD swizzle: 1024 blocks -> 8 contiguous 128-block chunks
    const int wid = (blockIdx.x & 7) * 128 + (blockIdx.x >> 3);
    const int gw  = wid * 4 + wave;          // 0..4095: (q-tile, p-strip)
    const int qt  = gw >> 5;                 // 0..127
    const int ps  = gw & 31;                 // 0..31
    const int q   = qt * 16 + l16;
    const int p0  = ps * 64;

    short8 fsp = *(const short8*)(spq + q * 64 + quad * 8);        // sp rows (B)
    short8 fnq = *(const short8*)(spq + q * 64 + 32 + quad * 8);   // -tq rows (B)

#pragma unroll
    for (int it = 0; it < 4; ++it) {
        int p = p0 + it * 16;
        short8 ftp = *(const short8*)(frag + (p + l16) * 64 + quad * 8);       // tp rows (A)
        short8 fx  = *(const short8*)(frag + (p + l16) * 64 + 32 + quad * 8);  // x rows (A)
        floatx4 acc = {0.f, 0.f, 0.f, 0.f};
        acc = __builtin_amdgcn_mfma_f32_16x16x32_bf16(ftp, fsp, acc, 0, 0, 0);
        acc = __builtin_amdgcn_mfma_f32_16x16x32_bf16(fx,  fnq, acc, 0, 0, 0);
        // acc[r] = D[row = quad*4+r (p-offset)][col = l16 (q)]
        floatx4 wq = *(const floatx4*)(W + q * PRE_ + p + quad * 4);
        floatx4 o;
#pragma unroll
        for (int r = 0; r < 4; ++r) {
            float wc = fminf(fmaxf(wq[r], -1.0f), 1.0f);
            o[r] = wc * acc[r];
        }
        *(floatx4*)(dw + q * PRE_ + p + quad * 4) = o;
    }
}

extern "C" void kernel_launch(void* const* d_in, const int* in_sizes, int n_in,
                              void* d_out, int out_size, void* d_ws, size_t ws_size,
                              hipStream_t stream) {
    const float* x     = (const float*)d_in[0];
    const float* W     = (const float*)d_in[1];
    const float* tpre  = (const float*)d_in[2];
    const float* tpost = (const float*)d_in[3];
    float* out = (float*)d_out;
    unsigned short* ws = (unsigned short*)d_ws;

    hipLaunchKernelGGL(stdp_fwd, dim3(POST_ / QT), dim3(512), 0, stream,
                       W, x, tpre, tpost, ws, out);
    hipLaunchKernelGGL(stdp_dw,  dim3(1024), dim3(256), 0, stream, W, ws, out);
}

// Round 3
// 92.569 us; speedup vs baseline: 1.1122x; 1.1122x over previous
//
#include <hip/hip_runtime.h>

#define B_ 32
#define PRE_ 2048
#define POST_ 2048
#define QT 8            // q rows per WG in fused kernel
#define WPAD 2056       // LDS row stride (shorts); 2056*2B = 16B-multiple

typedef __attribute__((ext_vector_type(8))) short short8;
typedef __attribute__((ext_vector_type(4))) short short4v;
typedef __attribute__((ext_vector_type(4))) float floatx4;

__device__ __forceinline__ unsigned short f2bf(float f) {
    unsigned u = __float_as_uint(f);
    u += 0x7FFF + ((u >> 16) & 1);   // round-to-nearest-even
    return (unsigned short)(u >> 16);
}
__device__ __forceinline__ float bf2f(unsigned short h) {
    return __uint_as_float(((unsigned)h) << 16);
}

// ws layout (unsigned short elements):
//   xrow [32][2048]        @ 0       x row-major bf16 (exact 0/1) - forward A-frags
//   frag [2048][64]        @ 65536   per p: [ tp_bf16(32 b) | x_bf16(32 b) ] - dw B-frags

__global__ __launch_bounds__(256) void stdp_prep(
    const float* __restrict__ x, const float* __restrict__ tpre,
    unsigned short* __restrict__ ws)
{
    int lin = blockIdx.x * 256 + threadIdx.x;    // 0..16383
    // phase A: xrow (row-major bf16), fully coalesced float4 in / 8B out
    int base = lin * 4;
    floatx4 xv = *(const floatx4*)(x + base);
    short4v xr;
#pragma unroll
    for (int j = 0; j < 4; ++j)
        xr[j] = (short)(__float_as_uint(xv[j]) >> 16);   // exact for {0,1}
    *(short4v*)(ws + base) = xr;

    // phase B: transposed frag rows; thread owns (p, 4 consecutive b) -> 8B stores
    int p  = lin >> 3;
    int b0 = (lin & 7) * 4;
    short4v tpv, xcv;
#pragma unroll
    for (int j = 0; j < 4; ++j) {
        float xx = x[(b0 + j) * PRE_ + p];
        float tt = tpre[(b0 + j) * PRE_ + p];
        tpv[j] = (short)f2bf(0.5f * tt + xx);            // tp, rounded bf16
        xcv[j] = (short)(__float_as_uint(xx) >> 16);
    }
    *(short4v*)(ws + 65536 + p * 64 + b0) = tpv;
    *(short4v*)(ws + 65536 + p * 64 + 32 + b0) = xcv;
}

// Fused: WG owns 8 q-rows. Wave-private W staging (k-slice == wave's K-split range
// == wave's dw p-range), forward split-bf16 MFMA -> spike, then dw with W from LDS.
__global__ __launch_bounds__(512) void stdp_fused(
    const float* __restrict__ W, const float* __restrict__ trace_post,
    const unsigned short* __restrict__ ws, float* __restrict__ out)
{
    __shared__ __align__(16) unsigned short Wh[QT * WPAD];   // 32.9 KB
    __shared__ __align__(16) unsigned short Wl[QT * WPAD];   // 32.9 KB
    __shared__ __align__(16) float red[8 * 2 * 4 * 64];      // 16 KB
    __shared__ __align__(16) unsigned short spnq[QT * 64];   // [q][ sp(32) | -tq(32) ]

    const int tid  = threadIdx.x;
    const int wave = tid >> 6, lane = tid & 63;
    const int quad = lane >> 4, l16 = lane & 15;
    const int q0   = blockIdx.x * QT;
    const int qb   = l16 & 7;
    const int kbase = wave * 256;     // wave's K-slice == its dw p-slice

    // prefetch trace_post for the post-barrier epilogue (waves 0,1 only)
    float tpr[4];
    if (wave < 2 && l16 < QT) {
#pragma unroll
        for (int r = 0; r < 4; ++r)
            tpr[r] = trace_post[(wave * 16 + quad * 4 + r) * POST_ + q0 + l16];
    }

    // ---- wave-private W staging: rows q0..q0+7, cols [kbase, kbase+256) ----
    floatx4 wv[8];
#pragma unroll
    for (int r = 0; r < 8; ++r)
        wv[r] = *(const floatx4*)(W + (q0 + r) * PRE_ + kbase + lane * 4);
#pragma unroll
    for (int r = 0; r < 8; ++r) {
        short4v hv, lv;
#pragma unroll
        for (int j = 0; j < 4; ++j) {
            unsigned short h = f2bf(wv[r][j]);
            hv[j] = (short)h;
            lv[j] = (short)f2bf(wv[r][j] - bf2f(h));
        }
        *(short4v*)&Wh[r * WPAD + kbase + lane * 4] = hv;
        *(short4v*)&Wl[r * WPAD + kbase + lane * 4] = lv;
    }

    // ---- forward: i[32 x 8] partial over wave's K-slice (no barrier needed:
    //      this wave wrote exactly the LDS it reads) ----
    const unsigned short* xrow = ws;
    floatx4 acc0 = {0.f, 0.f, 0.f, 0.f};
    floatx4 acc1 = {0.f, 0.f, 0.f, 0.f};
#pragma unroll
    for (int s = 0; s < 8; ++s) {
        int ko = kbase + s * 32 + quad * 8;
        short8 a0 = *(const short8*)(xrow + l16 * PRE_ + ko);
        short8 a1 = *(const short8*)(xrow + (16 + l16) * PRE_ + ko);
        short8 bh = *(const short8*)(Wh + qb * WPAD + ko);
        short8 bl = *(const short8*)(Wl + qb * WPAD + ko);
        acc0 = __builtin_amdgcn_mfma_f32_16x16x32_bf16(a0, bh, acc0, 0, 0, 0);
        acc0 = __builtin_amdgcn_mfma_f32_16x16x32_bf16(a0, bl, acc0, 0, 0, 0);
        acc1 = __builtin_amdgcn_mfma_f32_16x16x32_bf16(a1, bh, acc1, 0, 0, 0);
        acc1 = __builtin_amdgcn_mfma_f32_16x16x32_bf16(a1, bl, acc1, 0, 0, 0);
    }

    // prefetch first dw B-frags (independent of the barrier)
    const unsigned short* frag = ws + 65536;
    const int pbase = wave * 256;
    short8 ftp = *(const short8*)(frag + (pbase + l16) * 64 + quad * 8);
    short8 fx  = *(const short8*)(frag + (pbase + l16) * 64 + 32 + quad * 8);

    // ---- cross-wave K reduction ----
#pragma unroll
    for (int r = 0; r < 4; ++r) {
        red[((wave * 2 + 0) * 4 + r) * 64 + lane] = acc0[r];
        red[((wave * 2 + 1) * 4 + r) * 64 + lane] = acc1[r];
    }
    __syncthreads();

    if (wave < 2 && l16 < QT) {
        int q = q0 + l16;
#pragma unroll
        for (int r = 0; r < 4; ++r) {
            float s = 0.f;
#pragma unroll
            for (int w = 0; w < 8; ++w) s += red[((w * 2 + wave) * 4 + r) * 64 + lane];
            int b = wave * 16 + quad * 4 + r;
            float spike = (s >= 1.0f) ? 1.0f : 0.0f;
            out[b * POST_ + q] = spike;
            float ntq = -(0.5f * tpr[r] + spike);        // -tq, single rounded bf16
            spnq[l16 * 64 + b]      = f2bf(spike);
            spnq[l16 * 64 + 32 + b] = f2bf(ntq);
        }
    }
    __syncthreads();

    // ---- dw: wave's p-slice [pbase, pbase+256), K=32 -> 2 MFMAs/tile ----
    short8 fs  = *(const short8*)(spnq + qb * 64 + quad * 8);
    short8 fnq = *(const short8*)(spnq + qb * 64 + 32 + quad * 8);
    float* dw = out + B_ * POST_;

#pragma unroll 4
    for (int it = 0; it < 16; ++it) {
        // rotate-prefetch next B-frags (wraps harmlessly to it=0 at the end)
        int pn = (pbase + (((it + 1) & 15) * 16) + l16) * 64;
        short8 ntp = *(const short8*)(frag + pn + quad * 8);
        short8 nx  = *(const short8*)(frag + pn + 32 + quad * 8);

        floatx4 acc = {0.f, 0.f, 0.f, 0.f};
        acc = __builtin_amdgcn_mfma_f32_16x16x32_bf16(fs,  ftp, acc, 0, 0, 0);
        acc = __builtin_amdgcn_mfma_f32_16x16x32_bf16(fnq, fx,  acc, 0, 0, 0);

        int p = pbase + it * 16 + l16;
        if (quad < 2) {
#pragma unroll
            for (int r = 0; r < 4; ++r) {
                int qd = quad * 4 + r;
                float wvv = bf2f(Wh[qd * WPAD + p]) + bf2f(Wl[qd * WPAD + p]);
                wvv = fminf(fmaxf(wvv, -1.0f), 1.0f);
                dw[(q0 + qd) * PRE_ + p] = wvv * acc[r];
            }
        }
        ftp = ntp; fx = nx;
    }
}

extern "C" void kernel_launch(void* const* d_in, const int* in_sizes, int n_in,
                              void* d_out, int out_size, void* d_ws, size_t ws_size,
                              hipStream_t stream) {
    const float* x     = (const float*)d_in[0];
    const float* W     = (const float*)d_in[1];
    const float* tpre  = (const float*)d_in[2];
    const float* tpost = (const float*)d_in[3];
    float* out = (float*)d_out;
    unsigned short* ws = (unsigned short*)d_ws;

    hipLaunchKernelGGL(stdp_prep, dim3(64), dim3(256), 0, stream, x, tpre, ws);
    hipLaunchKernelGGL(stdp_fused, dim3(POST_ / QT), dim3(512), 0, stream,
                       W, tpost, ws, out);
}